// Round 1
// baseline (215.783 us; speedup 1.0000x reference)
//
#include <hip/hip_runtime.h>

// SphKernel: out[b,v,p,nr,ch] = g[nr] * Y[ch], one thread per point (b,v,p).
// Output staged through LDS so global stores are lane-consecutive (coalesced).
// LDS stride 49 floats/point: lane bank stride = 49 mod 32 = 17, coprime with
// 32 -> conflict-free scatter writes; sequential reads are stride-1 (free).

#define TPB 256
#define PT_VALS 48      // NR(3) * 16 channels
#define SM_STRIDE 49    // +1 pad for bank conflicts

__global__ __launch_bounds__(TPB) void sph_kernel(
    const float* __restrict__ patches,   // [N,3]
    const float* __restrict__ frames,    // [N/64, 9]
    const float* __restrict__ rr,        // [N]
    float* __restrict__ out,             // [N,48]
    int n_points)
{
    __shared__ float sm[TPB * SM_STRIDE];
    const int tid = threadIdx.x;
    const int q = blockIdx.x * TPB + tid;

    if (q < n_points) {
        // ---- load & normalize direction ----
        float d0 = patches[q * 3 + 0];
        float d1 = patches[q * 3 + 1];
        float d2 = patches[q * 3 + 2];
        float sq = d0 * d0 + d1 * d1 + d2 * d2;
        float inv = rsqrtf(fmaxf(sq, 1e-12f));
        d0 *= inv; d1 *= inv; d2 *= inv;

        // ---- rotate into local frame: proj_j = sum_i F[i][j] * d_i ----
        const int vb = (q >> 6) * 9;     // P = 64
        float x = frames[vb + 0] * d0 + frames[vb + 3] * d1 + frames[vb + 6] * d2;
        float y = frames[vb + 1] * d0 + frames[vb + 4] * d1 + frames[vb + 7] * d2;
        float z = frames[vb + 2] * d0 + frames[vb + 5] * d1 + frames[vb + 8] * d2;

        // ---- real SH up to l=3, reference channel order ----
        float x2 = x * x, y2 = y * y, z2 = z * z;
        float xy = x * y, yz = y * z, zx = z * x;
        float Y[16];
        Y[0]  = 0.28209479177387814f;                                  // Y00
        Y[1]  = 0.4886025119029199f * z;                               // Y100
        Y[2]  = 0.31539156525252005f * (2.0f * z2 - x2 - y2);          // Y200
        Y[3]  = 0.3731763325901154f * (2.0f * z2 * z - 3.0f * x2 * z - 3.0f * y2 * z); // Y300
        Y[4]  = 0.4886025119029199f * x;                               // Y1_10
        Y[5]  = 0.4886025119029199f * y;                               // Y1_11
        Y[6]  = 1.0925484305920792f * zx;                              // Y2_10
        Y[7]  = 1.0925484305920792f * yz;                              // Y2_11
        Y[8]  = 0.4570457994644658f * (4.0f * z2 * x - x2 * x - x * y2); // Y3_10
        Y[9]  = 0.4570457994644658f * (4.0f * y * z2 - x2 * y - y2 * y); // Y3_11
        Y[10] = 0.5462742152960396f * (x2 - y2);                       // Y2_20
        Y[11] = 1.0925484305920792f * xy;                              // Y2_21
        Y[12] = 1.4453057213202769f * (x2 * z - y2 * z);               // Y3_20
        Y[13] = 2.8906114426405538f * (xy * z);                        // Y3_21
        Y[14] = 0.5900435899266435f * (x2 * x - 3.0f * x * y2);        // Y3_30
        Y[15] = 0.5900435899266435f * (3.0f * x2 * y - y2 * y);        // Y3_31

        // ---- gaussian shells: centers {0, 0.5, 1}; exp(4 ln0.5 d^2)=2^(-4d^2)
        float rv = rr[q];
        float e0 = rv, e1 = rv - 0.5f, e2 = rv - 1.0f;
        float g0 = exp2f(-4.0f * e0 * e0);
        float g1 = exp2f(-4.0f * e1 * e1);
        float g2 = exp2f(-4.0f * e2 * e2);
        float gn = 1.0f / (g0 + g1 + g2);
        g0 *= gn; g1 *= gn; g2 *= gn;

        float* s = sm + tid * SM_STRIDE;
        #pragma unroll
        for (int c = 0; c < 16; ++c) {
            s[c]      = g0 * Y[c];
            s[16 + c] = g1 * Y[c];
            s[32 + c] = g2 * Y[c];
        }
    }
    __syncthreads();

    // ---- coalesced dump: consecutive lanes -> consecutive global addresses
    const size_t obase = (size_t)blockIdx.x * (TPB * PT_VALS);
    const size_t total = (size_t)n_points * PT_VALS;
    #pragma unroll
    for (int j = tid; j < TPB * PT_VALS; j += TPB) {
        size_t go = obase + (size_t)j;
        if (go < total) {
            out[go] = sm[(j / PT_VALS) * SM_STRIDE + (j % PT_VALS)];
        }
    }
}

extern "C" void kernel_launch(void* const* d_in, const int* in_sizes, int n_in,
                              void* d_out, int out_size, void* d_ws, size_t ws_size,
                              hipStream_t stream) {
    const float* patches = (const float*)d_in[0];  // [B,V,P,3]
    const float* frames  = (const float*)d_in[1];  // [B,V,3,3]
    const float* r       = (const float*)d_in[2];  // [B,V,P]
    float* out = (float*)d_out;                    // [B,V,P,3,16] f32

    const int n_points = in_sizes[2];              // B*V*P
    const int blocks = (n_points + TPB - 1) / TPB;
    sph_kernel<<<blocks, TPB, 0, stream>>>(patches, frames, r, out, n_points);
}

// Round 2
// 210.120 us; speedup vs baseline: 1.0270x; 1.0270x over previous
//
#include <hip/hip_runtime.h>

// SphKernel: out[b,v,p,shell,ch] = g[shell] * Y[ch]  (NR=3, 16 SH channels).
// Phase 1: one thread per point computes Y[16] + g[3], stages FACTORS in LDS
//          (planar float4 Y, planar g; plane stride 257 breaks bank aliasing).
// Phase 2: 12 float4 outputs per point, product formed on the fly, stores are
//          lane-consecutive float4 -> perfectly coalesced 1KB/wave-instr.
// LDS ~20KB/block -> 8 blocks/CU; write-BW-bound design (201 MB output).

#define TPB 256
#define YSTRIDE 257   // float4 plane stride: 257*4 dwords == 4 mod 32 banks
#define GSTRIDE 257

__global__ __launch_bounds__(TPB) void sph_kernel(
    const float* __restrict__ patches,   // [N,3]
    const float* __restrict__ frames,    // [N/64, 9]
    const float* __restrict__ rr,        // [N]
    float4* __restrict__ out4,           // [N,12]  (48 floats/point)
    int n_points)
{
    __shared__ float4 sY[4 * YSTRIDE];   // plane c4 holds Y[4*c4 .. 4*c4+3]
    __shared__ float  sG[3 * GSTRIDE];   // plane s holds g[s]

    const int tid = threadIdx.x;
    const int q = blockIdx.x * TPB + tid;

    if (q < n_points) {
        // ---- load & normalize direction ----
        float d0 = patches[q * 3 + 0];
        float d1 = patches[q * 3 + 1];
        float d2 = patches[q * 3 + 2];
        float sq = d0 * d0 + d1 * d1 + d2 * d2;
        float inv = rsqrtf(fmaxf(sq, 1e-12f));
        d0 *= inv; d1 *= inv; d2 *= inv;

        // ---- rotate into local frame: proj_j = sum_i F[i][j] * d_i ----
        const int vb = (q >> 6) * 9;     // P = 64 points per frame
        float x = frames[vb + 0] * d0 + frames[vb + 3] * d1 + frames[vb + 6] * d2;
        float y = frames[vb + 1] * d0 + frames[vb + 4] * d1 + frames[vb + 7] * d2;
        float z = frames[vb + 2] * d0 + frames[vb + 5] * d1 + frames[vb + 8] * d2;

        // ---- real SH up to l=3, reference channel order ----
        float x2 = x * x, y2 = y * y, z2 = z * z;
        float xy = x * y, yz = y * z, zx = z * x;
        float Y0  = 0.28209479177387814f;
        float Y1  = 0.4886025119029199f * z;
        float Y2  = 0.31539156525252005f * (2.0f * z2 - x2 - y2);
        float Y3  = 0.3731763325901154f * (2.0f * z2 * z - 3.0f * x2 * z - 3.0f * y2 * z);
        float Y4  = 0.4886025119029199f * x;
        float Y5  = 0.4886025119029199f * y;
        float Y6  = 1.0925484305920792f * zx;
        float Y7  = 1.0925484305920792f * yz;
        float Y8  = 0.4570457994644658f * (4.0f * z2 * x - x2 * x - x * y2);
        float Y9  = 0.4570457994644658f * (4.0f * y * z2 - x2 * y - y2 * y);
        float Y10 = 0.5462742152960396f * (x2 - y2);
        float Y11 = 1.0925484305920792f * xy;
        float Y12 = 1.4453057213202769f * (x2 * z - y2 * z);
        float Y13 = 2.8906114426405538f * (xy * z);
        float Y14 = 0.5900435899266435f * (x2 * x - 3.0f * x * y2);
        float Y15 = 0.5900435899266435f * (3.0f * x2 * y - y2 * y);

        // ---- gaussian shells: centers {0,0.5,1}; exp(4 ln0.5 d^2)=2^(-4 d^2)
        float rv = rr[q];
        float e1 = rv - 0.5f, e2 = rv - 1.0f;
        float g0 = exp2f(-4.0f * rv * rv);
        float g1 = exp2f(-4.0f * e1 * e1);
        float g2 = exp2f(-4.0f * e2 * e2);
        float gn = 1.0f / (g0 + g1 + g2);

        sY[0 * YSTRIDE + tid] = make_float4(Y0,  Y1,  Y2,  Y3);
        sY[1 * YSTRIDE + tid] = make_float4(Y4,  Y5,  Y6,  Y7);
        sY[2 * YSTRIDE + tid] = make_float4(Y8,  Y9,  Y10, Y11);
        sY[3 * YSTRIDE + tid] = make_float4(Y12, Y13, Y14, Y15);
        sG[0 * GSTRIDE + tid] = g0 * gn;
        sG[1 * GSTRIDE + tid] = g1 * gn;
        sG[2 * GSTRIDE + tid] = g2 * gn;
    }
    __syncthreads();

    // ---- phase 2: out4[p*12 + qc] = g[p][qc>>2] * Y4[p][qc&3] ----
    const size_t obase = (size_t)blockIdx.x * (TPB * 12);
    const size_t total4 = (size_t)n_points * 12;
    #pragma unroll
    for (int k = 0; k < 12; ++k) {
        int j = tid + k * TPB;
        int p = j / 12;
        int qc = j - p * 12;
        int shell = qc >> 2;
        int c4 = qc & 3;
        size_t go = obase + (size_t)j;
        if (go < total4) {
            float g = sG[shell * GSTRIDE + p];
            float4 yv = sY[c4 * YSTRIDE + p];
            float4 o;
            o.x = g * yv.x; o.y = g * yv.y; o.z = g * yv.z; o.w = g * yv.w;
            out4[go] = o;
        }
    }
}

extern "C" void kernel_launch(void* const* d_in, const int* in_sizes, int n_in,
                              void* d_out, int out_size, void* d_ws, size_t ws_size,
                              hipStream_t stream) {
    const float* patches = (const float*)d_in[0];  // [B,V,P,3]
    const float* frames  = (const float*)d_in[1];  // [B,V,3,3]
    const float* r       = (const float*)d_in[2];  // [B,V,P]
    float4* out4 = (float4*)d_out;                 // [B,V,P,3,16] f32

    const int n_points = in_sizes[2];              // B*V*P
    const int blocks = (n_points + TPB - 1) / TPB;
    sph_kernel<<<blocks, TPB, 0, stream>>>(patches, frames, r, out4, n_points);
}